// Round 1
// baseline (273.813 us; speedup 1.0000x reference)
//
#include <hip/hip_runtime.h>
#include <stdint.h>

// ---------------------------------------------------------------------------
// VectorQuantizer: argmin_k ||x_n - c_k||^2 + straight-through out + losses.
//
// Token semantics (R4/R5/R7/R9-verified): candidates by continuous score
// s = ||c||^2 - 2 x.c via fp16 MFMA; exact fp64 re-score; token = lowest
// index within 0.75*ulp_fp32(Dmin) of the minimum.
//
// R9: packed-key epilogue -> gemm 197->129us. R10: scratch-free refine ->
// total 309->279us. R11: per-block LDS colmin + private colmin_part slice
// (no global atomics).
// R12: gemm counters showed 58MB WRITE / 44MB FETCH vs ~4MB logical writes
// (~53 dwords/thread of scratch spill). Cause: full dc-unroll exposed 64
// in-flight fragment loads (256 VGPRs) + 48 persistent regs against the
// 256-reg cap of __launch_bounds__(256,2). Fix: explicit 2-deep register
// rotation for af/bf (bounded in-flight = 64 regs) and xsqr read from LDS
// in the epilogue instead of 16 persistent VGPRs.
// ---------------------------------------------------------------------------

#define N_ROWS 16384
#define DIM    256
#define KCODES 4096
#define NCHUNK 8
#define KC     (KCODES / NCHUNK)   // 512 codes per chunk
#define TM     128                 // rows per block tile
#define TN     128                 // codes per code-tile
#define BK     32                  // K per dc step
#define NKT    (KC / TN)           // 4 code tiles per chunk
#define NDC    (DIM / BK)          // 8 K-steps
#define NGRAN  (NCHUNK * 2)        // 16 granules of 256 cols (chunk x chalf)
#define NRB    (N_ROWS / TM)       // 128 row-blocks

typedef float    f32x4 __attribute__((ext_vector_type(4)));
typedef _Float16 f16x8 __attribute__((ext_vector_type(8)));

__device__ __forceinline__ unsigned umin_(unsigned a, unsigned b) { return a < b ? a : b; }
__device__ __forceinline__ unsigned umax_(unsigned a, unsigned b) { return a > b ? a : b; }

// order-preserving float->uint key
__device__ __forceinline__ unsigned fkey(float f) {
    unsigned b = __float_as_uint(f);
    return (b & 0x80000000u) ? ~b : (b | 0x80000000u);
}
__device__ __forceinline__ float fkey_inv(unsigned k) {
    unsigned b = (k & 0x80000000u) ? (k ^ 0x80000000u) : ~k;
    return __uint_as_float(b);
}
__device__ __forceinline__ unsigned short f2h(float f) {
    union { _Float16 h; unsigned short u; } cv;
    cv.h = (_Float16)f;            // v_cvt_f16_f32, RNE
    return cv.u;
}

// sorted top-8 insert by (value, index) lexicographic
__device__ __forceinline__ void ins8(float w, int j, float v[8], int id[8]) {
    if (w < v[7] || (w == v[7] && j < id[7])) {
        v[7] = w; id[7] = j;
#pragma unroll
        for (int k = 7; k > 0; --k) {
            if (v[k] < v[k-1] || (v[k] == v[k-1] && id[k] < id[k-1])) {
                float tv = v[k]; v[k] = v[k-1]; v[k-1] = tv;
                int ti = id[k]; id[k] = id[k-1]; id[k-1] = ti;
            }
        }
    }
}

// ---- prep: fp16 cast + row sumsq (fp64->fp32) + buffer init, fused ----
__global__ __launch_bounds__(256) void vq_prep_kernel(
        const float* __restrict__ x, const float* __restrict__ cb,
        unsigned short* __restrict__ xh, unsigned short* __restrict__ ch,
        float* __restrict__ xsq, float* __restrict__ csq,
        unsigned* __restrict__ active, double* __restrict__ accum,
        unsigned* __restrict__ counter) {
    const int b = blockIdx.x, t = threadIdx.x;
    if (b < KCODES / 256) {
        int i = b * 256 + t;
        active[i] = 0u;
        if (i == 0) { accum[0] = 0.0; accum[1] = 0.0; counter[0] = 0u; }
    }
    const size_t NX = (size_t)N_ROWS * DIM;
    size_t e = (size_t)b * 1024 + (size_t)t * 4;
    const float* src; unsigned short* dst; float* sq; size_t off;
    if (e < NX) { src = x;  dst = xh; sq = xsq; off = e; }
    else        { src = cb; dst = ch; sq = csq; off = e - NX; }
    float4 v = *(const float4*)(src + off);
    ushort4 h;
    h.x = f2h(v.x); h.y = f2h(v.y); h.z = f2h(v.z); h.w = f2h(v.w);
    *(ushort4*)(dst + off) = h;
    double s = (double)v.x * v.x + (double)v.y * v.y
             + (double)v.z * v.z + (double)v.w * v.w;
    for (int o = 32; o; o >>= 1) s += __shfl_down(s, o);
    if ((t & 63) == 0) sq[off >> 8] = (float)s;
}

// ---- MFMA candidate GEMM, barrier-free K-loop, packed-key epilogue.
// grid = (NRB, NCHUNK), 256 thr (4 waves, 2x2 of 64x64).
// R12: 2-deep register rotation for fragments; xsqr via LDS broadcast.
__global__ __launch_bounds__(256, 2) void vq_gemm_kernel(
        const unsigned short* __restrict__ xh_g, const unsigned short* __restrict__ ch_g,
        const float* __restrict__ xsq, const float* __restrict__ csq,
        unsigned* __restrict__ colmin_part, uint2* __restrict__ top2_out) {
    __shared__ float    xsq_l[128];
    __shared__ unsigned colmin_l[KC];

    const int t = threadIdx.x;
    const int wave = t >> 6, lane = t & 63, quad = lane >> 4, L = lane & 15;
    const int whalf = wave >> 1, chalf = wave & 1;
    const int row0  = blockIdx.x * TM;
    const int code0 = blockIdx.y * KC;

    if (t < 128) xsq_l[t] = xsq[row0 + t];
    colmin_l[t] = 0xFFFFFFFFu; colmin_l[t + 256] = 0xFFFFFFFFu;
    __syncthreads();

    const unsigned short* abase =
        xh_g + ((size_t)(row0 + whalf * 64 + L) * DIM + quad * 8);

    unsigned u1[16], u2[16];   // packed (quantized score | col9) running top-2
#pragma unroll
    for (int i = 0; i < 16; ++i) { u1[i] = 0xFFFFFFFFu; u2[i] = 0xFFFFFFFFu; }

    for (int kt = 0; kt < NKT; ++kt) {
        const int cb0 = code0 + kt * TN;
        const unsigned short* bbase =
            ch_g + ((size_t)(cb0 + chalf * 64 + L) * DIM + quad * 8);
        f32x4 acc[4][4];
#pragma unroll
        for (int mt = 0; mt < 4; ++mt)
#pragma unroll
            for (int nt = 0; nt < 4; ++nt) acc[mt][nt] = (f32x4){0.f, 0.f, 0.f, 0.f};

        // 2-deep rotation: bounded fragment in-flight (64 regs peak).
        f16x8 a0[4], b0[4], a1[4], b1[4];
#pragma unroll
        for (int mt = 0; mt < 4; ++mt)
            a0[mt] = *(const f16x8*)(abase + (size_t)mt * 16 * DIM);
#pragma unroll
        for (int nt = 0; nt < 4; ++nt)
            b0[nt] = *(const f16x8*)(bbase + (size_t)nt * 16 * DIM);

#pragma unroll
        for (int dc2 = 0; dc2 < NDC; dc2 += 2) {
            // prefetch dc2+1 into set 1
#pragma unroll
            for (int mt = 0; mt < 4; ++mt)
                a1[mt] = *(const f16x8*)(abase + (size_t)mt * 16 * DIM + (dc2 + 1) * BK);
#pragma unroll
            for (int nt = 0; nt < 4; ++nt)
                b1[nt] = *(const f16x8*)(bbase + (size_t)nt * 16 * DIM + (dc2 + 1) * BK);
            // consume set 0 (dc2)
#pragma unroll
            for (int mt = 0; mt < 4; ++mt)
#pragma unroll
                for (int nt = 0; nt < 4; ++nt)
                    acc[mt][nt] = __builtin_amdgcn_mfma_f32_16x16x32_f16(
                        a0[mt], b0[nt], acc[mt][nt], 0, 0, 0);
            // prefetch dc2+2 into set 0 (WAR-pinned below consuming MFMAs)
            if (dc2 + 2 < NDC) {
#pragma unroll
                for (int mt = 0; mt < 4; ++mt)
                    a0[mt] = *(const f16x8*)(abase + (size_t)mt * 16 * DIM + (dc2 + 2) * BK);
#pragma unroll
                for (int nt = 0; nt < 4; ++nt)
                    b0[nt] = *(const f16x8*)(bbase + (size_t)nt * 16 * DIM + (dc2 + 2) * BK);
            }
            // consume set 1 (dc2+1)
#pragma unroll
            for (int mt = 0; mt < 4; ++mt)
#pragma unroll
                for (int nt = 0; nt < 4; ++nt)
                    acc[mt][nt] = __builtin_amdgcn_mfma_f32_16x16x32_f16(
                        a1[mt], b1[nt], acc[mt][nt], 0, 0, 0);
        }

        // ---- epilogue: packed-key top-2 upkeep + column-min (LDS) ----
        float csq4[4]; unsigned colf[4];
        float dmin[4] = {3.4e38f, 3.4e38f, 3.4e38f, 3.4e38f};
#pragma unroll
        for (int nt = 0; nt < 4; ++nt) {
            csq4[nt] = csq[cb0 + chalf * 64 + nt * 16 + L];
            colf[nt] = (unsigned)(kt * 128 + chalf * 64 + nt * 16 + L);
        }
#pragma unroll
        for (int mt = 0; mt < 4; ++mt) {
            // broadcast read of 4 row-sumsq values (replaces 16 persistent regs)
            const f32x4 xq = *(const f32x4*)&xsq_l[whalf * 64 + mt * 16 + quad * 4];
#pragma unroll
            for (int reg = 0; reg < 4; ++reg) {
                const int i = mt * 4 + reg;
#pragma unroll
                for (int nt = 0; nt < 4; ++nt) {
                    float s = fmaf(-2.0f, acc[mt][nt][reg], csq4[nt]);
                    unsigned key = (fkey(s) & 0xFFFFFE00u) | colf[nt];
                    unsigned lo = umin_(u1[i], key);
                    u2[i] = umin_(u2[i], umax_(u1[i], key));
                    u1[i] = lo;
                    dmin[nt] = fminf(dmin[nt], xq[reg] + s);
                }
            }
        }
#pragma unroll
        for (int nt = 0; nt < 4; ++nt) {
            unsigned dk = fkey(dmin[nt]);
            dk = umin_(dk, (unsigned)__shfl_xor((int)dk, 16));
            dk = umin_(dk, (unsigned)__shfl_xor((int)dk, 32));
            if (quad == 0)
                atomicMin(&colmin_l[kt * TN + chalf * 64 + nt * 16 + L], dk);
        }
    }

    // ---- once per block: butterfly-merge top-2 across the 16 L-lanes ----
#pragma unroll
    for (int i = 0; i < 16; ++i) {
#pragma unroll
        for (int st = 1; st < 16; st <<= 1) {
            unsigned w1 = (unsigned)__shfl_xor((int)u1[i], st);
            unsigned w2 = (unsigned)__shfl_xor((int)u2[i], st);
            unsigned a = umin_(u1[i], w1), b = umax_(u1[i], w1);
            u1[i] = a;
            u2[i] = umin_(umin_(u2[i], w2), b);
        }
    }
    if (L == 0) {
        const size_t gbase = (size_t)(blockIdx.y * 2 + chalf) * N_ROWS;
#pragma unroll
        for (int mt = 0; mt < 4; ++mt)
#pragma unroll
            for (int reg = 0; reg < 4; ++reg) {
                const int row = row0 + whalf * 64 + mt * 16 + quad * 4 + reg;
                top2_out[gbase + row] = make_uint2(u1[mt * 4 + reg], u2[mt * 4 + reg]);
            }
    }

    // ---- flush block-local colmin to private slice (plain stores) ----
    __syncthreads();
    unsigned* cp = colmin_part + (size_t)blockIdx.x * KCODES + code0;
    cp[t]       = colmin_l[t];
    cp[t + 256] = colmin_l[t + 256];
}

// ---- refine + gather + MSE, fused. grid = N_ROWS/4, 1 wave per row. ----
// Fast path: candidate gap > 1e-2 => winner certain, no fp64. Slow path:
// all 8 candidates, fully unrolled fp64 re-score, token = lowest index
// within 0.75*ulp_fp32(Dmin). No dynamic indexing (no scratch).
__global__ __launch_bounds__(256) void vq_refine_kernel(
        const float* __restrict__ x, const float* __restrict__ cb,
        const uint2* __restrict__ top2, unsigned* __restrict__ active,
        float* __restrict__ out, double* __restrict__ accum) {
    __shared__ double wsum[4];
    const int wave = threadIdx.x >> 6, lane = threadIdx.x & 63;
    const int row  = blockIdx.x * 4 + wave;

    float v[8]; int id[8];
#pragma unroll
    for (int k = 0; k < 8; ++k) { v[k] = 3.4e38f; id[k] = 0x7FFFFFFF; }
#pragma unroll
    for (int g = 0; g < NGRAN; ++g) {
        uint2 e = top2[(size_t)g * N_ROWS + row];
        const int cbase = (g >> 1) * KC;
        ins8(fkey_inv(e.x & 0xFFFFFE00u), cbase + (int)(e.x & 0x1FFu), v, id);
        ins8(fkey_inv(e.y & 0xFFFFFE00u), cbase + (int)(e.y & 0x1FFu), v, id);
    }

    float4 xv = ((const float4*)(x + (size_t)row * DIM))[lane];
    int tok;
    if (v[1] > v[0] + 1.0e-2f) {
        tok = id[0];
    } else {
        double xs64 = (double)xv.x * xv.x + (double)xv.y * xv.y
                    + (double)xv.z * xv.z + (double)xv.w * xv.w;
        double dd[8], cc2[8];
#pragma unroll
        for (int k = 0; k < 8; ++k) {
            float4 c4 = ((const float4*)(cb + (size_t)id[k] * DIM))[lane];
            dd[k]  = (double)xv.x * c4.x + (double)xv.y * c4.y
                   + (double)xv.z * c4.z + (double)xv.w * c4.w;
            cc2[k] = (double)c4.x * c4.x + (double)c4.y * c4.y
                   + (double)c4.z * c4.z + (double)c4.w * c4.w;
        }
#pragma unroll
        for (int o = 32; o; o >>= 1) {
            xs64 += __shfl_down(xs64, o);
#pragma unroll
            for (int k = 0; k < 8; ++k) {
                dd[k]  += __shfl_down(dd[k], o);
                cc2[k] += __shfl_down(cc2[k], o);
            }
        }
        if (lane == 0) {
            double D[8], Dmin = 1e300;
#pragma unroll
            for (int k = 0; k < 8; ++k) {
                D[k] = xs64 + cc2[k] - 2.0 * dd[k];
                Dmin = fmin(Dmin, D[k]);
            }
            int e2; frexp(Dmin, &e2);
            double U   = ldexp(1.0, e2 - 1 - 23);     // ulp_fp32(Dmin)
            double thr = Dmin + 0.75 * U;
            tok = 0x7FFFFFFF;
#pragma unroll
            for (int k = 0; k < 8; ++k)
                if (D[k] <= thr && id[k] < tok) tok = id[k];
        }
        tok = __shfl(tok, 0);
    }

    if (lane == 0) active[tok] = 1u;
    float4 sel = ((const float4*)(cb + (size_t)tok * DIM))[lane];
    ((float4*)out)[(size_t)row * 64 + lane] = sel;
    float dx = sel.x - xv.x, dy = sel.y - xv.y, dz = sel.z - xv.z, dw = sel.w - xv.w;
    float s = dx * dx + dy * dy + dz * dz + dw * dw;
    for (int o = 32; o; o >>= 1) s += __shfl_down(s, o);
    if (lane == 0) wsum[wave] = (double)s;
    __syncthreads();
    if (threadIdx.x == 0) atomicAdd(accum, wsum[0] + wsum[1] + wsum[2] + wsum[3]);
}

// ---- final: 128-way colmin reduction + entropy + loss. grid = 16 blocks.
// Each block reduces 256 codes over the 128 row-block partials, adds its
// inactive-code entropy partial; the 16th finisher computes the loss.
__global__ __launch_bounds__(256) void vq_final_kernel(
        const unsigned* __restrict__ colmin_part, const unsigned* __restrict__ active,
        double* __restrict__ accum, unsigned* __restrict__ counter,
        float* __restrict__ out) {
    __shared__ double red[256];
    const int t = threadIdx.x;
    const int c = blockIdx.x * 256 + t;
    unsigned m = 0xFFFFFFFFu;
#pragma unroll 8
    for (int rb = 0; rb < NRB; ++rb)
        m = umin_(m, colmin_part[(size_t)rb * KCODES + c]);
    red[t] = (active[c] == 0u) ? (double)fkey_inv(m) : 0.0;
    __syncthreads();
    for (int o = 128; o; o >>= 1) {
        if (t < o) red[t] += red[t + o];
        __syncthreads();
    }
    if (t == 0) {
        atomicAdd(&accum[1], red[0]);
        __threadfence();
        unsigned old = atomicAdd(counter, 1u);
        if (old == 15u) {
            __threadfence();
            double ent = atomicAdd(&accum[1], 0.0);   // atomic read
            double loss = 1.25 * (accum[0] / (double)((size_t)N_ROWS * DIM))
                        + 0.02 * (ent / (double)KCODES);
            out[(size_t)N_ROWS * DIM] = (float)loss;
        }
    }
}

extern "C" void kernel_launch(void* const* d_in, const int* in_sizes, int n_in,
                              void* d_out, int out_size, void* d_ws, size_t ws_size,
                              hipStream_t stream) {
    const float* x  = (const float*)d_in[0];   // [16384, 256]
    const float* cb = (const float*)d_in[1];   // [4096, 256]
    float* out = (float*)d_out;                // [16384*256] ++ [1] loss

    char* ws = (char*)d_ws;
    float*    xsq     = (float*)(ws + 0);                      // 64 KB
    float*    csq     = (float*)(ws + 65536);                  // 16 KB
    unsigned* active  = (unsigned*)(ws + 81920);               // 16 KB
    double*   accum   = (double*)(ws + 98304);                 // 256 B (mse, entropy)
    unsigned* counter = (unsigned*)(ws + 98560);               // 64 B
    uint2*    top2    = (uint2*)(ws + 131072);                 // 2 MB (16 granules)
    unsigned* cpart   = (unsigned*)(ws + 2228224);             // 2 MB (128 x 4096)
    unsigned short* xh_g = (unsigned short*)(ws + 4325376);    // 8 MB
    unsigned short* ch_g = (unsigned short*)(ws + 12713984);   // 2 MB (~14.2 MB)

    vq_prep_kernel<<<((N_ROWS + KCODES) * DIM) / 1024, 256, 0, stream>>>(
        x, cb, xh_g, ch_g, xsq, csq, active, accum, counter);
    vq_gemm_kernel<<<dim3(NRB, NCHUNK), 256, 0, stream>>>(
        xh_g, ch_g, xsq, csq, cpart, top2);
    vq_refine_kernel<<<N_ROWS / 4, 256, 0, stream>>>(
        x, cb, top2, active, out, accum);
    vq_final_kernel<<<KCODES / 256, 256, 0, stream>>>(
        cpart, active, accum, counter, out);
}